// Round 2
// baseline (96730.713 us; speedup 1.0000x reference)
//
#include <hip/hip_runtime.h>
#include <cstdint>
#include <cstddef>

// Problem constants
#define BB 256     // batch
#define TT 512     // time steps
#define HH 512     // hidden
// L0 K-order: [x(0..255) | h0_prev(256..767) | ct_prev(768..895)]   K=896
// L1 K-order: [h1_prev(0..511) | h0_cur(512..1023)]                 K=1024
// 256 blocks = 4 m-groups (64 batch rows) x 64 s-slices (8 h-cols -> 32 gatecols/layer)
// W slices resident in LDS. c-state in registers. m-group-local flag sync.

typedef _Float16 f16;
typedef _Float16 f16x8 __attribute__((ext_vector_type(8)));
typedef float f32x4 __attribute__((ext_vector_type(4)));

// ---------------- threefry2x32 (key = (0,42)), jax_threefry_partitionable ----------------
__device__ __forceinline__ void tf_round(uint32_t& x0, uint32_t& x1, const int r) {
  x0 += x1;
  x1 = (x1 << r) | (x1 >> (32 - r));
  x1 ^= x0;
}

__device__ __forceinline__ void threefry2x32(uint32_t c0, uint32_t c1, uint32_t& o0, uint32_t& o1) {
  const uint32_t ks0 = 0u, ks1 = 42u;
  const uint32_t ks2 = 0x1BD11BDAu ^ ks0 ^ ks1;
  uint32_t x0 = c0 + ks0, x1 = c1 + ks1;
  tf_round(x0,x1,13); tf_round(x0,x1,15); tf_round(x0,x1,26); tf_round(x0,x1,6);
  x0 += ks1; x1 += ks2 + 1u;
  tf_round(x0,x1,17); tf_round(x0,x1,29); tf_round(x0,x1,16); tf_round(x0,x1,24);
  x0 += ks2; x1 += ks0 + 2u;
  tf_round(x0,x1,13); tf_round(x0,x1,15); tf_round(x0,x1,26); tf_round(x0,x1,6);
  x0 += ks0; x1 += ks1 + 3u;
  tf_round(x0,x1,17); tf_round(x0,x1,29); tf_round(x0,x1,16); tf_round(x0,x1,24);
  x0 += ks1; x1 += ks2 + 4u;
  tf_round(x0,x1,13); tf_round(x0,x1,15); tf_round(x0,x1,26); tf_round(x0,x1,6);
  x0 += ks2; x1 += ks0 + 5u;
  o0 = x0; o1 = x1;
}

__device__ __forceinline__ float gumbel_noise(uint32_t idx) {
  uint32_t o0, o1;
  threefry2x32(0u, idx, o0, o1);
  uint32_t bits = o0 ^ o1;
  uint32_t fb = (bits >> 9) | 0x3f800000u;
  float u = __uint_as_float(fb) - 1.0f;
  const float tiny = 1.17549435e-38f;
  u = fmaxf(tiny, u + tiny);
  return -logf(-logf(u));
}

// ---------------- m-group sync primitives (device-scope, acyclic -> no deadlock) ----------------
__device__ __forceinline__ void sync_arrive(uint32_t* cnt) {
  __threadfence();                 // release my stores (agent scope)
  __syncthreads();                 // all threads' fences done
  if (threadIdx.x == 0)
    __hip_atomic_fetch_add(cnt, 1u, __ATOMIC_RELEASE, __HIP_MEMORY_SCOPE_AGENT);
}

__device__ __forceinline__ void sync_wait(uint32_t* cnt, uint32_t target) {
  if (threadIdx.x == 0) {
    int guard = 0;                 // bounded spin: on logic bug, finish (wrong) instead of hang
    while (__hip_atomic_load(cnt, __ATOMIC_RELAXED, __HIP_MEMORY_SCOPE_AGENT) < target
           && guard < 200000) { __builtin_amdgcn_s_sleep(2); ++guard; }
  }
  __syncthreads();
  __threadfence();                 // acquire side (invalidate caches)
}

// ---------------- one LSTM layer phase: chunked GEMM (LDS-resident W) + cell ----------------
// Per block: 64 rows x 32 gatecols, K chunks of 64, A double-buffered in LDS (reg-staged).
// Wave w (8 waves): mu=w>>1 (16-row sub-tile), nu=w&1 (16-gatecol sub-tile); 2 accs (even/odd k).
template<int PH>
__device__ __forceinline__ void lstm_phase(
    int t, int m, int s, int tid,
    const float* __restrict__ states,
    const f16* __restrict__ seg_a,    // PH0: h0_prev ; PH1: h1_prev
    const f16* __restrict__ seg_b,    // PH0: ct_prev ; PH1: h0_cur
    const f16* __restrict__ Wxs, const int wstr,
    const float bi, const float bf, const float bg, const float bo,
    float& cR,
    f16* __restrict__ h_out,
    uint32_t* wait_cnt, uint32_t wait_target,
    f16 (*Abuf)[64][72], float (*glds)[33])
{
  constexpr int NC = PH ? 16 : 14;
  constexpr int CW = PH ? 8 : 12;   // chunk index whose staging needs the wait
  const int lane = tid & 63;
  const int wv = tid >> 6;
  const int mu = wv >> 1;
  const int nu = wv & 1;
  const int ra = lane & 15;
  const int kg = (lane >> 4) << 3;
  const int srow = tid >> 3;        // staging row 0..63
  const int sk = (tid & 7) << 3;    // staging k-offset within chunk
  const int brow = m * 64 + srow;

  f32x4 acce = {0.f,0.f,0.f,0.f}, acco = {0.f,0.f,0.f,0.f};
  f16x8 sreg;

  auto stage = [&](int j) {
    const int kk = j * 64 + sk;
    if (PH == 0) {
      if (kk < 256) {
        const float* p = states + ((size_t)brow * TT + t) * 256 + kk;
        f32x4 u = *(const f32x4*)p;
        f32x4 v = *(const f32x4*)(p + 4);
        sreg[0]=(f16)u[0]; sreg[1]=(f16)u[1]; sreg[2]=(f16)u[2]; sreg[3]=(f16)u[3];
        sreg[4]=(f16)v[0]; sreg[5]=(f16)v[1]; sreg[6]=(f16)v[2]; sreg[7]=(f16)v[3];
      } else if (kk < 768) {
        sreg = *(const f16x8*)(seg_a + (size_t)brow * 512 + (kk - 256));
      } else {
        sreg = *(const f16x8*)(seg_b + (size_t)brow * 128 + (kk - 768));
      }
    } else {
      if (kk < 512) sreg = *(const f16x8*)(seg_a + (size_t)brow * 512 + kk);
      else          sreg = *(const f16x8*)(seg_b + (size_t)brow * 512 + (kk - 512));
    }
  };

  stage(0);
  *(f16x8*)&Abuf[0][srow][sk] = sreg;
  __syncthreads();

  for (int j = 0; j < NC; ++j) {
    const int cb = j & 1;
    if (j + 1 < NC) {
      if (j + 1 == CW && wait_cnt) sync_wait(wait_cnt, wait_target);
      stage(j + 1);                 // issue global loads early (hide under MFMA)
    }
    f16x8 ae = *(const f16x8*)&Abuf[cb][mu*16 + ra][kg];
    f16x8 ao = *(const f16x8*)&Abuf[cb][mu*16 + ra][32 + kg];
    const f16* wp = Wxs + (size_t)(nu*16 + ra) * wstr + j * 64;
    f16x8 be = *(const f16x8*)(wp + kg);
    f16x8 bo = *(const f16x8*)(wp + 32 + kg);
    acce = __builtin_amdgcn_mfma_f32_16x16x32_f16(ae, be, acce, 0, 0, 0);
    acco = __builtin_amdgcn_mfma_f32_16x16x32_f16(ao, bo, acco, 0, 0, 0);
    if (j + 1 < NC) {
      *(f16x8*)&Abuf[cb ^ 1][srow][sk] = sreg;
      __syncthreads();
    }
  }
  __syncthreads();                  // all ds_reads done before glds alias writes

  f32x4 acc = acce + acco;
  const int crow = (lane >> 4) << 2;
  #pragma unroll
  for (int r = 0; r < 4; ++r)
    glds[mu*16 + crow + r][nu*16 + ra] = acc[r];   // C/D: col=lane&15, row=(lane>>4)*4+r
  __syncthreads();

  // cell epilogue: thread -> (row = tid>>3, hc = tid&7); gate lc = g*8+hc
  const int erow = tid >> 3, ehc = tid & 7;
  float gI = glds[erow][ehc]      + bi;
  float gF = glds[erow][8 + ehc]  + bf;
  float gG = glds[erow][16 + ehc] + bg;
  float gO = glds[erow][24 + ehc] + bo;
  float si = 1.0f / (1.0f + expf(-gI));
  float sf = 1.0f / (1.0f + expf(-gF));
  float so = 1.0f / (1.0f + expf(-gO));
  float cn = sf * cR + si * tanhf(gG);
  cR = cn;
  h_out[(size_t)(m*64 + erow) * 512 + s*8 + ehc] = (f16)(so * tanhf(cn));
}

// ---------------- the persistent kernel ----------------
__global__ __launch_bounds__(512, 2) void persistent_kernel(
    const float* __restrict__ states,
    const float* __restrict__ Wih0, const float* __restrict__ Whh0,
    const float* __restrict__ bih0, const float* __restrict__ bhh0,
    const float* __restrict__ Wih1, const float* __restrict__ Whh1,
    const float* __restrict__ bih1, const float* __restrict__ bhh1,
    const float* __restrict__ Wlin, const float* __restrict__ blin,
    float* __restrict__ out,
    uint32_t* cnt0, uint32_t* cnt1, uint32_t* cnt2, uint32_t* flag3,
    f16* h0buf, f16* h1buf, f16* ctbuf, f16* Wlc)
{
  __shared__ __align__(16) f16 W0s[32][904];   // 57,856 B  (k-pad +8: 2-way banks, 16B rows)
  __shared__ __align__(16) f16 W1s[32][1032];  // 66,048 B
  __shared__ __align__(16) f16 Abuf[2][64][72];// 18,432 B  (total 142,336 <= 160 KiB)
  float (*glds)[33] = reinterpret_cast<float(*)[33]>(&Abuf[0][0][0]);  // aliased epilogue buf

  const int tid = threadIdx.x;
  const int bid = blockIdx.x;
  const int m = bid & 3;            // m-group: XCD x hosts only m = x&3 -> L2 locality
  const int s = bid >> 2;           // 0..63

  // ---- one-time init: W slices -> LDS (f32->f16, reordered K) ----
  {
    const int lc = tid & 31;
    const int gr = ((lc >> 3) << 9) + s*8 + (lc & 7);   // gate*512 + hcol
    for (int k = tid >> 5; k < 896; k += 16) {
      float v;
      if (k < 256)      v = Wih0[(size_t)gr * 384 + k];            // x part
      else if (k < 768) v = Whh0[(size_t)gr * 512 + (k - 256)];    // h0_prev part
      else              v = Wih0[(size_t)gr * 384 + 256 + (k - 768)]; // ct part
      W0s[lc][k] = (f16)v;
    }
    for (int k = tid >> 5; k < 1024; k += 16) {
      float v = (k < 512) ? Whh1[(size_t)gr * 512 + k]             // h1_prev part
                          : Wih1[(size_t)gr * 512 + (k - 512)];    // h0_cur part
      W1s[lc][k] = (f16)v;
    }
  }
  // ---- global init (partitioned; visible after start barrier) ----
  if (bid < 16) {
    for (int e = tid; e < 4096; e += 512) {
      int idx = bid * 4096 + e;
      Wlc[idx] = (f16)Wlin[idx];
    }
  }
  {
    const int erow = tid >> 3, ehc = tid & 7;
    h0buf[(size_t)(256 + m*64 + erow) * 512 + s*8 + ehc] = (f16)0.f;  // prev buf (idx 1)
    h1buf[(size_t)(256 + m*64 + erow) * 512 + s*8 + ehc] = (f16)0.f;
  }
  if (s < 4) {
    for (int e = tid; e < 2048; e += 512) {
      int row = e >> 5, col = e & 31;
      int gc = s*32 + col;
      ctbuf[(size_t)(256 + m*64 + row) * 128 + gc] = (f16)(((gc & 15) == 0) ? 1.f : 0.f);
    }
  }
  // ---- per-thread constants ----
  const int ehc = tid & 7;
  const int hcol = s*8 + ehc;
  const float bi0 = bih0[hcol]        + bhh0[hcol];
  const float bf0 = bih0[512 + hcol]  + bhh0[512 + hcol];
  const float bg0 = bih0[1024 + hcol] + bhh0[1024 + hcol];
  const float bo0 = bih0[1536 + hcol] + bhh0[1536 + hcol];
  const float bi1 = bih1[hcol]        + bhh1[hcol];
  const float bf1 = bih1[512 + hcol]  + bhh1[512 + hcol];
  const float bg1 = bih1[1024 + hcol] + bhh1[1024 + hcol];
  const float bo1 = bih1[1536 + hcol] + bhh1[1536 + hcol];
  float c0r = 0.f, c1r = 0.f;

  // ---- global start barrier (one-time) ----
  sync_arrive(cnt0);
  sync_wait(cnt0, 256u);

  const int lane = tid & 63;
  const int wv = tid >> 6;
  const int mu = wv >> 1;
  const int nu = wv & 1;
  const int ra = lane & 15;
  const int kg = (lane >> 4) << 3;

  for (int t = 0; t < TT; ++t) {
    const int cur = t & 1, prv = cur ^ 1;
    const f16* h0p = h0buf + (size_t)prv * BB * HH;
    f16*       h0c = h0buf + (size_t)cur * BB * HH;
    const f16* h1p = h1buf + (size_t)prv * BB * HH;
    f16*       h1c = h1buf + (size_t)cur * BB * HH;
    const f16* ctp = ctbuf + (size_t)prv * BB * 128;
    f16*       ctc = ctbuf + (size_t)cur * BB * 128;

    // Layer 0 (wait for ct[t-1] only right before the ct K-chunks)
    lstm_phase<0>(t, m, s, tid, states, h0p, ctp, &W0s[0][0], 904,
                  bi0, bf0, bg0, bo0, c0r, h0c,
                  (t > 0) ? &flag3[m*512 + (t-1)] : nullptr, 4u, Abuf, glds);
    sync_arrive(&cnt1[m*512 + t]);

    // Layer 1 (wait for all h0[t] of this m-group before the h0_cur K-chunks)
    lstm_phase<1>(t, m, s, tid, states, h1p, h0c, &W1s[0][0], 1032,
                  bi1, bf1, bg1, bo1, c1r, h1c,
                  &cnt1[m*512 + t], 64u, Abuf, glds);
    sync_arrive(&cnt2[m*512 + t]);

    // Q + gumbel-softmax (rotating duty: 4 s-slices per m-group per step)
    const int di = (s - 4*t) & 63;
    if (di < 4) {
      sync_wait(&cnt2[m*512 + t], 64u);
      f32x4 q0 = {0.f,0.f,0.f,0.f}, q1 = {0.f,0.f,0.f,0.f};
      const f16* arow = h1c + (size_t)(m*64 + mu*16 + ra) * 512;
      const f16* wr0 = Wlc + (size_t)(di*32 + ra) * 512;
      const f16* wr1 = Wlc + (size_t)(di*32 + 16 + ra) * 512;
      #pragma unroll 4
      for (int it = 0; it < 16; ++it) {
        const int k = it*32 + kg;
        f16x8 av = *(const f16x8*)(arow + k);
        f16x8 b0 = *(const f16x8*)(wr0 + k);
        f16x8 b1 = *(const f16x8*)(wr1 + k);
        q0 = __builtin_amdgcn_mfma_f32_16x16x32_f16(av, b0, q0, 0, 0, 0);
        q1 = __builtin_amdgcn_mfma_f32_16x16x32_f16(av, b1, q1, 0, 0, 0);
      }
      const int crow = (lane >> 4) << 2;
      #pragma unroll
      for (int nn = 0; nn < 2; ++nn) {
        f32x4 qa = nn ? q1 : q0;
        const int qc = di*32 + nn*16 + ra;       // c = qc&15 = ra, l = qc>>4 = di*2+nn
        const float bl = blin[qc];
        float y[4];
        #pragma unroll
        for (int r = 0; r < 4; ++r) {
          const int br = m*64 + mu*16 + crow + r;
          const uint32_t idx = (((uint32_t)t * 256u + (uint32_t)br) * 8u
                                + (uint32_t)(di*2 + nn)) * 16u + (uint32_t)ra;
          y[r] = (qa[r] + bl + gumbel_noise(idx)) / 0.1f;
        }
        #pragma unroll
        for (int r = 0; r < 4; ++r) {
          float mx = y[r];
          #pragma unroll
          for (int msk = 1; msk < 16; msk <<= 1) mx = fmaxf(mx, __shfl_xor(mx, msk));
          float ex = expf(y[r] - mx);
          float sm = ex;
          #pragma unroll
          for (int msk = 1; msk < 16; msk <<= 1) sm += __shfl_xor(sm, msk);
          y[r] = ex / sm;
        }
        #pragma unroll
        for (int r = 0; r < 4; ++r) {
          const int br = m*64 + mu*16 + crow + r;
          out[((size_t)br * TT + t) * 128 + qc] = y[r];
          ctc[(size_t)br * 128 + qc] = (f16)y[r];
        }
      }
      sync_arrive(&flag3[m*512 + t]);
    }
  }
}

// ---------------- host ----------------
extern "C" void kernel_launch(void* const* d_in, const int* in_sizes, int n_in,
                              void* d_out, int out_size, void* d_ws, size_t ws_size,
                              hipStream_t stream) {
  const float* states = (const float*)d_in[0];
  const float* Wih0 = (const float*)d_in[1];
  const float* Whh0 = (const float*)d_in[2];
  const float* bih0 = (const float*)d_in[3];
  const float* bhh0 = (const float*)d_in[4];
  const float* Wih1 = (const float*)d_in[5];
  const float* Whh1 = (const float*)d_in[6];
  const float* bih1 = (const float*)d_in[7];
  const float* bhh1 = (const float*)d_in[8];
  const float* Wlin = (const float*)d_in[9];
  const float* blin = (const float*)d_in[10];
  float* out = (float*)d_out;
  (void)in_sizes; (void)n_in; (void)out_size; (void)ws_size;

  char* ws = (char*)d_ws;
  size_t off = 0;
  auto alloc = [&](size_t bytes) -> void* {
    void* p = ws + off;
    off += (bytes + 255) & ~(size_t)255;
    return p;
  };
  uint32_t* cnt1  = (uint32_t*)alloc(4 * 512 * 4);   // [4][512]
  uint32_t* cnt2  = (uint32_t*)alloc(4 * 512 * 4);
  uint32_t* flag3 = (uint32_t*)alloc(4 * 512 * 4);
  uint32_t* cnt0  = (uint32_t*)alloc(4);
  const size_t cnt_bytes = off;                      // all counters at front
  f16* h0buf = (f16*)alloc(2ull * BB * HH * 2);
  f16* h1buf = (f16*)alloc(2ull * BB * HH * 2);
  f16* ctbuf = (f16*)alloc(2ull * BB * 128 * 2);
  f16* Wlc   = (f16*)alloc(128ull * 512 * 2);

  hipMemsetAsync(d_ws, 0, cnt_bytes, stream);
  persistent_kernel<<<256, 512, 0, stream>>>(
      states, Wih0, Whh0, bih0, bhh0, Wih1, Whh1, bih1, bhh1, Wlin, blin,
      out, cnt0, cnt1, cnt2, flag3, h0buf, h1buf, ctbuf, Wlc);
}

// Round 4
// 24350.305 us; speedup vs baseline: 3.9725x; 3.9725x over previous
//
#include <hip/hip_runtime.h>
#include <cstdint>
#include <cstddef>

// Problem constants
#define BB 256     // batch
#define TT 512     // time steps
#define HH 512     // hidden
// 256 blocks = 4 m-groups (64 batch rows) x 64 s-slices (8 h-cols = 32 gatecols/layer).
// Weights LDS-resident. c-state in regs. ct redundant per block (LDS-local).
// ALL cross-block data via __hip_atomic intrinsics (AGENT scope); flags RELEASE/ACQUIRE.
// No inline asm anywhere; chunk pipeline is compiler-managed (register-staged loads +
// double-buffered LDS + __syncthreads per chunk).

typedef _Float16 f16;
typedef _Float16 f16x8 __attribute__((ext_vector_type(8)));
typedef float f32x4 __attribute__((ext_vector_type(4)));

// ---------------- threefry2x32 (key = (0,42)), jax_threefry_partitionable ----------------
__device__ __forceinline__ void tf_round(uint32_t& x0, uint32_t& x1, const int r) {
  x0 += x1;
  x1 = (x1 << r) | (x1 >> (32 - r));
  x1 ^= x0;
}

__device__ __forceinline__ void threefry2x32(uint32_t c0, uint32_t c1, uint32_t& o0, uint32_t& o1) {
  const uint32_t ks0 = 0u, ks1 = 42u;
  const uint32_t ks2 = 0x1BD11BDAu ^ ks0 ^ ks1;
  uint32_t x0 = c0 + ks0, x1 = c1 + ks1;
  tf_round(x0,x1,13); tf_round(x0,x1,15); tf_round(x0,x1,26); tf_round(x0,x1,6);
  x0 += ks1; x1 += ks2 + 1u;
  tf_round(x0,x1,17); tf_round(x0,x1,29); tf_round(x0,x1,16); tf_round(x0,x1,24);
  x0 += ks2; x1 += ks0 + 2u;
  tf_round(x0,x1,13); tf_round(x0,x1,15); tf_round(x0,x1,26); tf_round(x0,x1,6);
  x0 += ks0; x1 += ks1 + 3u;
  tf_round(x0,x1,17); tf_round(x0,x1,29); tf_round(x0,x1,16); tf_round(x0,x1,24);
  x0 += ks1; x1 += ks2 + 4u;
  tf_round(x0,x1,13); tf_round(x0,x1,15); tf_round(x0,x1,26); tf_round(x0,x1,6);
  x0 += ks2; x1 += ks0 + 5u;
  o0 = x0; o1 = x1;
}

__device__ __forceinline__ float gumbel_noise(uint32_t idx) {
  uint32_t o0, o1;
  threefry2x32(0u, idx, o0, o1);
  uint32_t bits = o0 ^ o1;
  uint32_t fb = (bits >> 9) | 0x3f800000u;
  float u = __uint_as_float(fb) - 1.0f;
  const float tiny = 1.17549435e-38f;
  u = fmaxf(tiny, u + tiny);
  return -logf(-logf(u));
}

// ---------------- sync primitives (compiler-correct coherence) ----------------
__device__ __forceinline__ void release_add(uint32_t* p) {
  __hip_atomic_fetch_add(p, 1u, __ATOMIC_RELEASE, __HIP_MEMORY_SCOPE_AGENT);
}
__device__ __forceinline__ void spin_acquire(uint32_t* p, uint32_t tgt) {
  if (threadIdx.x == 0) {
    int g = 0;   // bounded: on logic bug, finish (finite-wrong) instead of hang
    while (__hip_atomic_load(p, __ATOMIC_RELAXED, __HIP_MEMORY_SCOPE_AGENT) < tgt && g < 100000) {
      __builtin_amdgcn_s_sleep(1); ++g;
    }
    (void)__hip_atomic_load(p, __ATOMIC_ACQUIRE, __HIP_MEMORY_SCOPE_AGENT);
  }
  __syncthreads();
}
__device__ __forceinline__ uint64_t aload64(const f16* p) {
  return __hip_atomic_load((const uint64_t*)p, __ATOMIC_RELAXED, __HIP_MEMORY_SCOPE_AGENT);
}
__device__ __forceinline__ void astore64(f16* p, uint64_t v) {
  __hip_atomic_store((uint64_t*)p, v, __ATOMIC_RELAXED, __HIP_MEMORY_SCOPE_AGENT);
}

// one MFMA pair on a 64-k chunk (even k half + odd k half)
#define MFMA2(AP, BP) { \
  f16x8 ae_ = *(const f16x8*)((AP) + kg); \
  f16x8 ao_ = *(const f16x8*)((AP) + 32 + kg); \
  f16x8 be_ = *(const f16x8*)((BP) + kg); \
  f16x8 bo_ = *(const f16x8*)((BP) + 32 + kg); \
  acce = __builtin_amdgcn_mfma_f32_16x16x32_f16(ae_, be_, acce, 0, 0, 0); \
  acco = __builtin_amdgcn_mfma_f32_16x16x32_f16(ao_, bo_, acco, 0, 0, 0); }

__device__ __forceinline__ f16x8 cvt8(f32x4 a, f32x4 b) {
  f16x8 w;
  w[0]=(f16)a[0]; w[1]=(f16)a[1]; w[2]=(f16)a[2]; w[3]=(f16)a[3];
  w[4]=(f16)b[0]; w[5]=(f16)b[1]; w[6]=(f16)b[2]; w[7]=(f16)b[3];
  return w;
}

// ---------------- the persistent kernel ----------------
__global__ __launch_bounds__(512, 2) void persistent_kernel(
    const float* __restrict__ states,
    const float* __restrict__ Wih0, const float* __restrict__ Whh0,
    const float* __restrict__ bih0, const float* __restrict__ bhh0,
    const float* __restrict__ Wih1, const float* __restrict__ Whh1,
    const float* __restrict__ bih1, const float* __restrict__ bhh1,
    const float* __restrict__ Wlin, const float* __restrict__ blin,
    float* __restrict__ out,
    uint32_t* cnt0, uint32_t* cntA, uint32_t* cntB,
    f16* h0buf, f16* h1buf, f16* Wlc)
{
  // all row strides ≡ 4 dwords (mod 32) -> worst 2-way bank aliasing (free, m136)
  __shared__ __align__(16) f16 W0s[32][904];    // 57,856 B
  __shared__ __align__(16) f16 W1s[32][1032];   // 66,048 B
  __shared__ __align__(16) f16 ctl[64][136];    // 17,408 B
  __shared__ __align__(16) f16 Abuf[2][64][72]; // 18,432 B  (total 159,744 <= 160 KiB)
  float (*glds)[36] = reinterpret_cast<float(*)[36]>(&Abuf[0][0][0]);  // 9,216B = Abuf[0]
  f16 (*hstage)[8]  = reinterpret_cast<f16(*)[8]>(&Abuf[1][0][0]);     // 1 KB in Abuf[1]

  const int tid = threadIdx.x;
  const int bid = blockIdx.x;
  const int m = bid & 3;            // m-group (64 batch rows)
  const int s = bid >> 2;           // h-col slice 0..63 (8 cols)
  const int lane = tid & 63;
  const int wv = tid >> 6;
  const int mu = wv >> 1;           // 16-row tile 0..3
  const int nu = wv & 1;            // 16-gatecol tile 0..1 (Q: 64-col tile)
  const int ra = lane & 15;
  const int kg = (lane >> 4) << 3;
  const int crow = (lane >> 4) << 2;
  const int srow = tid >> 3;        // staging row 0..63
  const int sk = (tid & 7) << 3;    // staging k offset (f16)
  const int ehc = tid & 7;

  // ---- one-time LDS W init (f32 -> f16, reordered K) ----
  {
    const int lc = tid & 31;
    const int gr = ((lc >> 3) << 9) + s*8 + (lc & 7);   // gate*512 + hcol
    for (int k = tid >> 5; k < 896; k += 16) {
      float v;
      if (k < 256)      v = Wih0[(size_t)gr * 384 + k];              // x
      else if (k < 768) v = Whh0[(size_t)gr * 512 + (k - 256)];      // h0_prev
      else              v = Wih0[(size_t)gr * 384 + 256 + (k - 768)];// ct
      W0s[lc][k] = (f16)v;
    }
    for (int k = tid >> 5; k < 1024; k += 16) {
      float v = (k < 512) ? Whh1[(size_t)gr * 512 + k]               // h1_prev
                          : Wih1[(size_t)gr * 512 + (k - 512)];      // h0_cur
      W1s[lc][k] = (f16)v;
    }
  }
  for (int e = tid; e < 64 * 128; e += 512)
    ctl[e >> 7][e & 127] = (f16)(((e & 15) == 0) ? 1.f : 0.f);

  // ---- global init: Wlc (atomic u32), h both parities zero (atomic u64) ----
  if (tid < 128) {
    const int e2 = bid * 128 + tid;                    // u32 index into Wlc
    union { f16 h[2]; uint32_t u; } pk2;
    pk2.h[0] = (f16)Wlin[2*e2]; pk2.h[1] = (f16)Wlin[2*e2 + 1];
    __hip_atomic_store((uint32_t*)Wlc + e2, pk2.u, __ATOMIC_RELAXED, __HIP_MEMORY_SCOPE_AGENT);
  }
  if (tid < 64) {
    #pragma unroll
    for (int par = 0; par < 2; ++par) {
      f16* p0 = h0buf + (size_t)(par*BB + m*64 + tid) * 512 + s*8;
      f16* p1 = h1buf + (size_t)(par*BB + m*64 + tid) * 512 + s*8;
      astore64(p0, 0ull); astore64(p0 + 4, 0ull);
      astore64(p1, 0ull); astore64(p1 + 4, 0ull);
    }
  }
  __syncthreads();
  if (tid == 0) release_add(cnt0);
  spin_acquire(cnt0, 256u);

  // ---- per-thread constants ----
  const int hcol = s*8 + ehc;
  const float bi0 = bih0[hcol]        + bhh0[hcol];
  const float bf0 = bih0[512 + hcol]  + bhh0[512 + hcol];
  const float bg0 = bih0[1024 + hcol] + bhh0[1024 + hcol];
  const float bo0 = bih0[1536 + hcol] + bhh0[1536 + hcol];
  const float bi1 = bih1[hcol]        + bhh1[hcol];
  const float bf1 = bih1[512 + hcol]  + bhh1[512 + hcol];
  const float bg1 = bih1[1024 + hcol] + bhh1[1024 + hcol];
  const float bo1 = bih1[1536 + hcol] + bhh1[1536 + hcol];
  float c0r = 0.f, c1r = 0.f;

  for (int t = 0; t < TT; ++t) {
    const int cur = t & 1, prv = cur ^ 1;
    f16* h0c_w = h0buf + (size_t)(cur*BB + m*64) * 512 + s*8;
    f16* h1c_w = h1buf + (size_t)(cur*BB + m*64) * 512 + s*8;
    const f16* h0p_b = h0buf + (size_t)(prv*BB + m*64 + srow) * 512 + sk;
    const f16* h1p_b = h1buf + (size_t)(prv*BB + m*64 + srow) * 512 + sk;
    const f16* h0c_b = h0buf + (size_t)(cur*BB + m*64 + srow) * 512 + sk;
    const f16* h1c_b = h1buf + (size_t)(cur*BB + m*64 + srow) * 512 + sk;
    const float* x_b = states + ((size_t)(m*64 + srow) * TT + t) * 256 + sk;

    // ---- stage this step's independent inputs into registers ----
    f32x4 xf[8];
    #pragma unroll
    for (int j = 0; j < 4; ++j) {
      xf[2*j]   = *(const f32x4*)(x_b + j*64);
      xf[2*j+1] = *(const f32x4*)(x_b + j*64 + 4);
    }
    uint64_t h0p[16], h1p[16];
    #pragma unroll
    for (int j = 0; j < 8; ++j) {
      h0p[2*j]   = aload64(h0p_b + j*64);
      h0p[2*j+1] = aload64(h0p_b + j*64 + 4);
      h1p[2*j]   = aload64(h1p_b + j*64);
      h1p[2*j+1] = aload64(h1p_b + j*64 + 4);
    }

    // ================= Layer 0: K = [x(0..3) | h0_prev(4..11) | ct_local(12..13)] =======
    {
      f32x4 acce = {0.f,0.f,0.f,0.f}, acco = {0.f,0.f,0.f,0.f};
      { f16x8 w = cvt8(xf[0], xf[1]); *(f16x8*)&Abuf[0][srow][sk] = w; }
      __syncthreads();
      #pragma unroll
      for (int j = 0; j < 14; ++j) {
        const int jn = j + 1;
        if (jn < 4) {
          f16x8 w = cvt8(xf[2*jn], xf[2*jn+1]);
          *(f16x8*)&Abuf[jn & 1][srow][sk] = w;
        } else if (jn < 12) {
          *(uint64_t*)&Abuf[jn & 1][srow][sk]     = h0p[2*(jn-4)];
          *(uint64_t*)&Abuf[jn & 1][srow][sk + 4] = h0p[2*(jn-4)+1];
        }
        const f16* ap = (j < 12) ? &Abuf[j & 1][mu*16 + ra][0]
                                 : &ctl[mu*16 + ra][(j - 12) * 64];
        MFMA2(ap, &W0s[nu*16 + ra][j * 64]);
        if (j < 12) __syncthreads();
      }
      f32x4 acc_ = acce + acco;
      #pragma unroll
      for (int r = 0; r < 4; ++r)
        glds[mu*16 + crow + r][nu*16 + ra] = acc_[r];   // C/D: col=lane&15, row=(lane>>4)*4+r
    }
    __syncthreads();
    {
      float gI = glds[srow][ehc]      + bi0;
      float gF = glds[srow][8 + ehc]  + bf0;
      float gG = glds[srow][16 + ehc] + bg0;
      float gO = glds[srow][24 + ehc] + bo0;
      float si = 1.0f / (1.0f + expf(-gI));
      float sf = 1.0f / (1.0f + expf(-gF));
      float so = 1.0f / (1.0f + expf(-gO));
      float cn = sf * c0r + si * tanhf(gG);
      c0r = cn;
      hstage[srow][ehc] = (f16)(so * tanhf(cn));
    }
    __syncthreads();
    if (wv == 0) {                       // wave 0 publishes the block's h0 slice
      uint64_t u0 = *(uint64_t*)&hstage[lane][0];
      uint64_t u1 = *(uint64_t*)&hstage[lane][4];
      astore64(h0c_w + (size_t)lane * 512,     u0);
      astore64(h0c_w + (size_t)lane * 512 + 4, u1);
      if (tid == 0) release_add(&cntA[(m << 9) + t]);   // RELEASE: drains wave's stores first
    }

    // ================= Layer 1: K = [h1_prev(0..7) | h0_cur(8..15)] =================
    {
      f32x4 acce = {0.f,0.f,0.f,0.f}, acco = {0.f,0.f,0.f,0.f};
      *(uint64_t*)&Abuf[0][srow][sk]     = h1p[0];
      *(uint64_t*)&Abuf[0][srow][sk + 4] = h1p[1];
      __syncthreads();
      uint64_t h0c[16];
      #pragma unroll
      for (int j = 0; j < 16; ++j) {
        if (j == 6) {                    // wait + load h0_cur with 1-chunk latency cover
          spin_acquire(&cntA[(m << 9) + t], 64u);
          #pragma unroll
          for (int q_ = 0; q_ < 8; ++q_) {
            h0c[2*q_]   = aload64(h0c_b + q_*64);
            h0c[2*q_+1] = aload64(h0c_b + q_*64 + 4);
          }
        }
        const int jn = j + 1;
        if (jn < 8) {
          *(uint64_t*)&Abuf[jn & 1][srow][sk]     = h1p[2*jn];
          *(uint64_t*)&Abuf[jn & 1][srow][sk + 4] = h1p[2*jn+1];
        } else if (jn < 16) {
          *(uint64_t*)&Abuf[jn & 1][srow][sk]     = h0c[2*(jn-8)];
          *(uint64_t*)&Abuf[jn & 1][srow][sk + 4] = h0c[2*(jn-8)+1];
        }
        MFMA2(&Abuf[j & 1][mu*16 + ra][0], &W1s[nu*16 + ra][j * 64]);
        __syncthreads();
      }
      f32x4 acc_ = acce + acco;
      #pragma unroll
      for (int r = 0; r < 4; ++r)
        glds[mu*16 + crow + r][nu*16 + ra] = acc_[r];
    }
    __syncthreads();
    {
      float gI = glds[srow][ehc]      + bi1;
      float gF = glds[srow][8 + ehc]  + bf1;
      float gG = glds[srow][16 + ehc] + bg1;
      float gO = glds[srow][24 + ehc] + bo1;
      float si = 1.0f / (1.0f + expf(-gI));
      float sf = 1.0f / (1.0f + expf(-gF));
      float so = 1.0f / (1.0f + expf(-gO));
      float cn = sf * c1r + si * tanhf(gG);
      c1r = cn;
      hstage[srow][ehc] = (f16)(so * tanhf(cn));
    }
    __syncthreads();
    if (wv == 0) {
      uint64_t u0 = *(uint64_t*)&hstage[lane][0];
      uint64_t u1 = *(uint64_t*)&hstage[lane][4];
      astore64(h1c_w + (size_t)lane * 512,     u0);
      astore64(h1c_w + (size_t)lane * 512 + 4, u1);
      if (tid == 0) release_add(&cntB[(m << 9) + t]);
    }

    // ================= Q + gumbel softmax (redundant per block, ct -> LDS) =============
    spin_acquire(&cntB[(m << 9) + t], 64u);
    {
      uint64_t h1c[16];
      #pragma unroll
      for (int q_ = 0; q_ < 8; ++q_) {
        h1c[2*q_]   = aload64(h1c_b + q_*64);
        h1c[2*q_+1] = aload64(h1c_b + q_*64 + 4);
      }
      const f16* wq = Wlc + (size_t)(nu*64 + ra) * 512 + kg;
      f32x4 accq[4] = {{0.f,0.f,0.f,0.f},{0.f,0.f,0.f,0.f},{0.f,0.f,0.f,0.f},{0.f,0.f,0.f,0.f}};
      *(uint64_t*)&Abuf[0][srow][sk]     = h1c[0];
      *(uint64_t*)&Abuf[0][srow][sk + 4] = h1c[1];
      __syncthreads();
      #pragma unroll
      for (int j = 0; j < 8; ++j) {
        const int jn = j + 1;
        if (jn < 8) {
          *(uint64_t*)&Abuf[jn & 1][srow][sk]     = h1c[2*jn];
          *(uint64_t*)&Abuf[jn & 1][srow][sk + 4] = h1c[2*jn+1];
        }
        f16x8 ae = *(const f16x8*)&Abuf[j & 1][mu*16 + ra][kg];
        f16x8 ao = *(const f16x8*)&Abuf[j & 1][mu*16 + ra][32 + kg];
        #pragma unroll
        for (int n_ = 0; n_ < 4; ++n_) {
          f16x8 bE = *(const f16x8*)(wq + (size_t)n_*8192 + j*64);
          f16x8 bO = *(const f16x8*)(wq + (size_t)n_*8192 + j*64 + 32);
          accq[n_] = __builtin_amdgcn_mfma_f32_16x16x32_f16(ae, bE, accq[n_], 0, 0, 0);
          accq[n_] = __builtin_amdgcn_mfma_f32_16x16x32_f16(ao, bO, accq[n_], 0, 0, 0);
        }
        __syncthreads();
      }

      const bool duty = (s == (t & 63));
      #pragma unroll
      for (int n_ = 0; n_ < 4; ++n_) {
        const int qc = nu*64 + n_*16 + ra;        // col 0..127
        const float bl = blin[qc];
        #pragma unroll
        for (int r = 0; r < 4; ++r) {
          const int rl = mu*16 + crow + r;        // local row 0..63
          const uint32_t nidx = (((uint32_t)t * 256u + (uint32_t)(m*64 + rl)) * 8u
                                 + (uint32_t)(qc >> 4)) * 16u + (uint32_t)ra;
          float v = (accq[n_][r] + bl + gumbel_noise(nidx)) / 0.1f;
          float mx = v;
          #pragma unroll
          for (int k_ = 1; k_ < 16; k_ <<= 1) mx = fmaxf(mx, __shfl_xor(mx, k_));
          float ex = expf(v - mx);
          float sm = ex;
          #pragma unroll
          for (int k_ = 1; k_ < 16; k_ <<= 1) sm += __shfl_xor(sm, k_);
          float y = ex / sm;
          ctl[rl][qc] = (f16)y;
          if (duty)
            out[((size_t)(m*64 + rl) * TT + t) * 128 + qc] = y;
        }
      }
    }
    __syncthreads();   // ctl + Abuf reuse safe for next step
  }
}

// ---------------- host ----------------
extern "C" void kernel_launch(void* const* d_in, const int* in_sizes, int n_in,
                              void* d_out, int out_size, void* d_ws, size_t ws_size,
                              hipStream_t stream) {
  const float* states = (const float*)d_in[0];
  const float* Wih0 = (const float*)d_in[1];
  const float* Whh0 = (const float*)d_in[2];
  const float* bih0 = (const float*)d_in[3];
  const float* bhh0 = (const float*)d_in[4];
  const float* Wih1 = (const float*)d_in[5];
  const float* Whh1 = (const float*)d_in[6];
  const float* bih1 = (const float*)d_in[7];
  const float* bhh1 = (const float*)d_in[8];
  const float* Wlin = (const float*)d_in[9];
  const float* blin = (const float*)d_in[10];
  float* out = (float*)d_out;
  (void)in_sizes; (void)n_in; (void)out_size; (void)ws_size;

  char* ws = (char*)d_ws;
  uint32_t* cntA = (uint32_t*)ws;                       // [4][512] = 8192 B
  uint32_t* cntB = (uint32_t*)(ws + 8192);              // 8192 B
  uint32_t* cnt0 = (uint32_t*)(ws + 16384);             // 4 B (pad to 256)
  const size_t cnt_bytes = 16640;
  f16* h0buf = (f16*)(ws + cnt_bytes);                  // 2*256*512*2 = 524,288 B
  f16* h1buf = (f16*)(ws + cnt_bytes + 524288);         // 524,288 B
  f16* Wlc   = (f16*)(ws + cnt_bytes + 2 * 524288);     // 131,072 B

  hipMemsetAsync(ws, 0, cnt_bytes, stream);
  persistent_kernel<<<256, 512, 0, stream>>>(
      states, Wih0, Whh0, bih0, bhh0, Wih1, Whh1, bih1, bhh1, Wlin, blin,
      out, cnt0, cntA, cntB, h0buf, h1buf, Wlc);
}

// Round 5
// 15898.724 us; speedup vs baseline: 6.0842x; 1.5316x over previous
//
#include <hip/hip_runtime.h>
#include <cstdint>
#include <cstddef>

// Problem constants
#define BB 256     // batch
#define TT 512     // time steps
#define HH 512     // hidden
// 256 blocks = 4 m-groups (64 batch rows) x 64 s-slices (8 h-cols = 32 gatecols/layer).
// Weights LDS-resident. c-state in regs. ct redundant per block (LDS-local).
// Cross-block h + flags: RELAXED agent atomics only (bypass L1/L2 to LLC) -- the ONLY
// cache-maintaining release/acquire is the one-time startup barrier (also scrubs
// poisoned/stale L2 lines so Wlc/noise can be plain L2-cached loads afterwards).
// Ordering: s_waitcnt vmcnt(0) before flag add; compiler fence + __syncthreads after poll.
// Pipeline: L0 x/h0-chunks run BEFORE the cntB(t-1) wait (hides flag latency);
// Q(t-1)'s h1 registers are reused as L1(t)'s h1_prev operand.

typedef _Float16 f16;
typedef _Float16 f16x8 __attribute__((ext_vector_type(8)));
typedef float f32x4 __attribute__((ext_vector_type(4)));

union U16B { uint64_t u[2]; f16x8 v; };

// ---------------- threefry2x32 (key = (0,42)), jax_threefry_partitionable ----------------
__device__ __forceinline__ void tf_round(uint32_t& x0, uint32_t& x1, const int r) {
  x0 += x1;
  x1 = (x1 << r) | (x1 >> (32 - r));
  x1 ^= x0;
}

__device__ __forceinline__ void threefry2x32(uint32_t c0, uint32_t c1, uint32_t& o0, uint32_t& o1) {
  const uint32_t ks0 = 0u, ks1 = 42u;
  const uint32_t ks2 = 0x1BD11BDAu ^ ks0 ^ ks1;
  uint32_t x0 = c0 + ks0, x1 = c1 + ks1;
  tf_round(x0,x1,13); tf_round(x0,x1,15); tf_round(x0,x1,26); tf_round(x0,x1,6);
  x0 += ks1; x1 += ks2 + 1u;
  tf_round(x0,x1,17); tf_round(x0,x1,29); tf_round(x0,x1,16); tf_round(x0,x1,24);
  x0 += ks2; x1 += ks0 + 2u;
  tf_round(x0,x1,13); tf_round(x0,x1,15); tf_round(x0,x1,26); tf_round(x0,x1,6);
  x0 += ks0; x1 += ks1 + 3u;
  tf_round(x0,x1,17); tf_round(x0,x1,29); tf_round(x0,x1,16); tf_round(x0,x1,24);
  x0 += ks1; x1 += ks2 + 4u;
  tf_round(x0,x1,13); tf_round(x0,x1,15); tf_round(x0,x1,26); tf_round(x0,x1,6);
  x0 += ks2; x1 += ks0 + 5u;
  o0 = x0; o1 = x1;
}

__device__ __forceinline__ float gumbel_bits_to_f(uint32_t bits, bool fast) {
  uint32_t fb = (bits >> 9) | 0x3f800000u;
  float u = __uint_as_float(fb) - 1.0f;
  const float tiny = 1.17549435e-38f;
  u = fmaxf(tiny, u + tiny);
  if (fast) return -__logf(-__logf(u));
  return -logf(-logf(u));
}

__device__ __forceinline__ float gumbel_noise(uint32_t idx, bool fast) {
  uint32_t o0, o1;
  threefry2x32(0u, idx, o0, o1);
  return gumbel_bits_to_f(o0 ^ o1, fast);
}

// ---------------- fast transcendentals (errors ~1e-6, tolerance is 2e-2) ----------------
__device__ __forceinline__ float fsig(float x) {
  return __builtin_amdgcn_rcpf(1.0f + __expf(-x));
}
__device__ __forceinline__ float ftanh(float x) {
  float xx = fminf(fmaxf(x, -15.f), 15.f);
  float t = __expf(2.f * xx);
  return (t - 1.f) * __builtin_amdgcn_rcpf(t + 1.f);
}

// ---------------- atomics (relaxed agent = LLC-direct, no cache maintenance) ----------------
__device__ __forceinline__ uint64_t aload64(const f16* p) {
  return __hip_atomic_load((const uint64_t*)p, __ATOMIC_RELAXED, __HIP_MEMORY_SCOPE_AGENT);
}
__device__ __forceinline__ void astore64(f16* p, uint64_t v) {
  __hip_atomic_store((uint64_t*)p, v, __ATOMIC_RELAXED, __HIP_MEMORY_SCOPE_AGENT);
}
__device__ __forceinline__ void flag_add_relaxed(uint32_t* p) {
  __hip_atomic_fetch_add(p, 1u, __ATOMIC_RELAXED, __HIP_MEMORY_SCOPE_AGENT);
}

__device__ __forceinline__ f16x8 cvt8(f32x4 a, f32x4 b) {
  f16x8 w;
  w[0]=(f16)a[0]; w[1]=(f16)a[1]; w[2]=(f16)a[2]; w[3]=(f16)a[3];
  w[4]=(f16)b[0]; w[5]=(f16)b[1]; w[6]=(f16)b[2]; w[7]=(f16)b[3];
  return w;
}

// ---------------- the persistent kernel ----------------
template<bool PRE>
__global__ __launch_bounds__(512, 2) void persistent_kernel(
    const float* __restrict__ states,
    const float* __restrict__ Wih0, const float* __restrict__ Whh0,
    const float* __restrict__ bih0, const float* __restrict__ bhh0,
    const float* __restrict__ Wih1, const float* __restrict__ Whh1,
    const float* __restrict__ bih1, const float* __restrict__ bhh1,
    const float* __restrict__ Wlin, const float* __restrict__ blin,
    float* __restrict__ out,
    uint32_t* cnt0, uint32_t* cntA, uint32_t* cntB,
    f16* h0buf, f16* h1buf, f16* Wlc, float* noise_pre)
{
  __shared__ __align__(16) f16 W0s[32][904];    // 57,856 B
  __shared__ __align__(16) f16 W1s[32][1032];   // 66,048 B
  __shared__ __align__(16) f16 ctl[64][136];    // 17,408 B
  __shared__ __align__(16) f16 Abuf[2][64][72]; // 18,432 B  (total 159,744 <= 160 KiB)
  float (*glds)[36] = reinterpret_cast<float(*)[36]>(&Abuf[0][0][0]);  // alias Abuf[0]
  f16 (*hstage)[8]  = reinterpret_cast<f16(*)[8]>(&Abuf[1][0][0]);     // alias Abuf[1]

  const int tid = threadIdx.x;
  const int bid = blockIdx.x;
  const int m = bid & 3;            // m-group (64 batch rows)
  const int s = bid >> 2;           // h-col slice 0..63 (8 cols)
  const int lane = tid & 63;
  const int wv = tid >> 6;
  const int mu = wv >> 1;           // 16-row tile 0..3
  const int nu = wv & 1;            // 16-gatecol tile (Q: 64-col tile)
  const int ra = lane & 15;
  const int kg = (lane >> 4) << 3;
  const int crow = (lane >> 4) << 2;
  const int srow = tid >> 3;        // staging row 0..63
  const int sk = (tid & 7) << 3;    // staging k offset (f16)
  const int ehc = tid & 7;

  // ---- one-time LDS W init (f32 -> f16, reordered K) ----
  {
    const int lc = tid & 31;
    const int gr = ((lc >> 3) << 9) + s*8 + (lc & 7);   // gate*512 + hcol
    for (int k = tid >> 5; k < 896; k += 16) {
      float v;
      if (k < 256)      v = Wih0[(size_t)gr * 384 + k];              // x
      else if (k < 768) v = Whh0[(size_t)gr * 512 + (k - 256)];      // h0_prev
      else              v = Wih0[(size_t)gr * 384 + 256 + (k - 768)];// ct
      W0s[lc][k] = (f16)v;
    }
    for (int k = tid >> 5; k < 1024; k += 16) {
      float v = (k < 512) ? Whh1[(size_t)gr * 512 + k]               // h1_prev
                          : Wih1[(size_t)gr * 512 + (k - 512)];      // h0_cur
      W1s[lc][k] = (f16)v;
    }
  }
  for (int e = tid; e < 64 * 128; e += 512)
    ctl[e >> 7][e & 127] = (f16)(((e & 15) == 0) ? 1.f : 0.f);

  // ---- global init: Wlc + noise (PLAIN stores; flushed by the startup RELEASE) ----
  if (tid < 128) {
    const int e2 = bid * 128 + tid;
    union { f16 h[2]; uint32_t u; } pk2;
    pk2.h[0] = (f16)Wlin[2*e2]; pk2.h[1] = (f16)Wlin[2*e2 + 1];
    ((uint32_t*)Wlc)[e2] = pk2.u;
  }
  if (PRE) {
    const uint32_t base = (uint32_t)bid * 65536u;
    for (uint32_t e = tid; e < 65536u; e += 512u)
      noise_pre[base + e] = gumbel_noise(base + e, false);
  }
  if (tid < 64) {
    #pragma unroll
    for (int par = 0; par < 2; ++par) {
      f16* p0 = h0buf + (size_t)(par*BB + m*64 + tid) * 512 + s*8;
      f16* p1 = h1buf + (size_t)(par*BB + m*64 + tid) * 512 + s*8;
      astore64(p0, 0ull); astore64(p0 + 4, 0ull);
      astore64(p1, 0ull); astore64(p1 + 4, 0ull);
    }
  }
  // ---- startup barrier: the ONLY cache-maintaining release/acquire ----
  __syncthreads();
  if (tid == 0) {
    __hip_atomic_fetch_add(cnt0, 1u, __ATOMIC_RELEASE, __HIP_MEMORY_SCOPE_AGENT);  // wbl2
    int g = 0;
    while (__hip_atomic_load(cnt0, __ATOMIC_RELAXED, __HIP_MEMORY_SCOPE_AGENT) < 256u && g < 2000000) {
      __builtin_amdgcn_s_sleep(1); ++g;
    }
    (void)__hip_atomic_load(cnt0, __ATOMIC_ACQUIRE, __HIP_MEMORY_SCOPE_AGENT);     // inv
  }
  __syncthreads();

  // ---- per-thread constants ----
  const int hcol = s*8 + ehc;
  const float bi0 = bih0[hcol]        + bhh0[hcol];
  const float bf0 = bih0[512 + hcol]  + bhh0[512 + hcol];
  const float bg0 = bih0[1024 + hcol] + bhh0[1024 + hcol];
  const float bo0 = bih0[1536 + hcol] + bhh0[1536 + hcol];
  const float bi1 = bih1[hcol]        + bhh1[hcol];
  const float bf1 = bih1[512 + hcol]  + bhh1[512 + hcol];
  const float bg1 = bih1[1024 + hcol] + bhh1[1024 + hcol];
  const float bo1 = bih1[1536 + hcol] + bhh1[1536 + hcol];
  float blv[4];
  #pragma unroll
  for (int n_ = 0; n_ < 4; ++n_) blv[n_] = blin[nu*64 + n_*16 + ra];
  float c0r = 0.f, c1r = 0.f;

  f32x4 acce, acco;
  U16B h1c[8], h0p[8], h0c[8];
  f32x4 xf[8];

  auto spin = [&](uint32_t* p, uint32_t tgt) {
    if (tid == 0) {
      int g = 0;
      while (__hip_atomic_load(p, __ATOMIC_RELAXED, __HIP_MEMORY_SCOPE_AGENT) < tgt && g < 1000000) {
        __builtin_amdgcn_s_sleep(1); ++g;
      }
    }
    asm volatile("" ::: "memory");   // compiler fence (no HW cache ops needed: data is LLC-direct)
    __syncthreads();
  };
  auto stageA = [&](int buf, f16x8 w) { *(f16x8*)&Abuf[buf][srow][sk] = w; };
  auto mfma2 = [&](const f16* ap, const f16* wp) {
    f16x8 ae = *(const f16x8*)(ap + kg);
    f16x8 ao = *(const f16x8*)(ap + 32 + kg);
    f16x8 be = *(const f16x8*)(wp + kg);
    f16x8 bo = *(const f16x8*)(wp + 32 + kg);
    acce = __builtin_amdgcn_mfma_f32_16x16x32_f16(ae, be, acce, 0, 0, 0);
    acco = __builtin_amdgcn_mfma_f32_16x16x32_f16(ao, bo, acco, 0, 0, 0);
  };

  // ---- Q phase for step tq: wait h1(tq), GEMM q, gumbel softmax -> ctl + out row ----
  auto qphase = [&](int tq) {
    spin(&cntB[(m << 9) + tq], 64u);
    const f16* h1c_b = h1buf + (size_t)((tq & 1)*BB + m*64 + srow) * 512 + sk;
    #pragma unroll
    for (int q_ = 0; q_ < 8; ++q_) {
      h1c[q_].u[0] = aload64(h1c_b + q_*64);
      h1c[q_].u[1] = aload64(h1c_b + q_*64 + 4);
    }
    float nz[4][4];
    if (PRE) {
      const float* npp = noise_pre + ((size_t)tq*256 + m*64 + mu*16 + crow)*128 + nu*64 + ra;
      #pragma unroll
      for (int n_ = 0; n_ < 4; ++n_)
        #pragma unroll
        for (int r = 0; r < 4; ++r) nz[n_][r] = npp[(size_t)r*128 + n_*16];
    }
    const f16* wq = Wlc + (size_t)(nu*64 + ra) * 512 + kg;
    f16x8 bE[2][4], bO[2][4];
    #pragma unroll
    for (int n_ = 0; n_ < 4; ++n_) {
      bE[0][n_] = *(const f16x8*)(wq + n_*8192);
      bO[0][n_] = *(const f16x8*)(wq + n_*8192 + 32);
    }
    f32x4 accq[4] = {{0,0,0,0},{0,0,0,0},{0,0,0,0},{0,0,0,0}};
    stageA(0, h1c[0].v);
    __syncthreads();
    #pragma unroll
    for (int j = 0; j < 8; ++j) {
      const int jn = j + 1;
      if (jn < 8) stageA(jn & 1, h1c[jn].v);
      if (j < 7) {
        #pragma unroll
        for (int n_ = 0; n_ < 4; ++n_) {
          bE[jn & 1][n_] = *(const f16x8*)(wq + n_*8192 + jn*64);
          bO[jn & 1][n_] = *(const f16x8*)(wq + n_*8192 + jn*64 + 32);
        }
      }
      f16x8 ae = *(const f16x8*)&Abuf[j & 1][mu*16 + ra][kg];
      f16x8 ao = *(const f16x8*)&Abuf[j & 1][mu*16 + ra][32 + kg];
      #pragma unroll
      for (int n_ = 0; n_ < 4; ++n_) {
        accq[n_] = __builtin_amdgcn_mfma_f32_16x16x32_f16(ae, bE[j & 1][n_], accq[n_], 0, 0, 0);
        accq[n_] = __builtin_amdgcn_mfma_f32_16x16x32_f16(ao, bO[j & 1][n_], accq[n_], 0, 0, 0);
      }
      __syncthreads();
    }
    #pragma unroll
    for (int n_ = 0; n_ < 4; ++n_) {
      const int qc = nu*64 + n_*16 + ra;
      #pragma unroll
      for (int r = 0; r < 4; ++r) {
        const int rl = mu*16 + crow + r;
        float g;
        if (PRE) g = nz[n_][r];
        else {
          const uint32_t nidx = (((uint32_t)tq * 256u + (uint32_t)(m*64 + rl)) * 128u + (uint32_t)qc);
          g = gumbel_noise(nidx, true);
        }
        float v = (accq[n_][r] + blv[n_] + g) * 10.0f;
        float mx = v;
        #pragma unroll
        for (int k_ = 1; k_ < 16; k_ <<= 1) mx = fmaxf(mx, __shfl_xor(mx, k_));
        float ex = __expf(v - mx);
        float sm = ex;
        #pragma unroll
        for (int k_ = 1; k_ < 16; k_ <<= 1) sm += __shfl_xor(sm, k_);
        float y = ex * __builtin_amdgcn_rcpf(sm);
        ctl[rl][qc] = (f16)y;
      }
    }
    __syncthreads();   // ctl final
    if (tid < 128)     // this block publishes exactly row m*64+s (coalesced 512 B)
      out[((size_t)(m*64 + s) * TT + tq) * 128 + tid] = (float)ctl[s][tid];
  };

  // ==================== main recurrence ====================
  for (int t = 0; t < TT; ++t) {
    const int cur = t & 1, prv = cur ^ 1;
    f16* h0c_w = h0buf + (size_t)(cur*BB + m*64) * 512 + s*8;
    f16* h1c_w = h1buf + (size_t)(cur*BB + m*64) * 512 + s*8;
    const f16* h0p_b = h0buf + (size_t)(prv*BB + m*64 + srow) * 512 + sk;
    const f16* h0c_b = h0buf + (size_t)(cur*BB + m*64 + srow) * 512 + sk;
    const float* x_b = states + ((size_t)(m*64 + srow) * TT + t) * 256 + sk;

    // stage x (plain, L2) + h0_prev (atomic, LLC) into registers
    #pragma unroll
    for (int j = 0; j < 4; ++j) {
      xf[2*j]   = *(const f32x4*)(x_b + j*64);
      xf[2*j+1] = *(const f32x4*)(x_b + j*64 + 4);
    }
    #pragma unroll
    for (int j = 0; j < 8; ++j) {
      h0p[j].u[0] = aload64(h0p_b + j*64);
      h0p[j].u[1] = aload64(h0p_b + j*64 + 4);
    }

    // ---- L0 part A: chunks 0..11 (x, h0_prev) — before the cntB wait ----
    acce = f32x4{0,0,0,0}; acco = f32x4{0,0,0,0};
    stageA(0, cvt8(xf[0], xf[1]));
    __syncthreads();
    #pragma unroll
    for (int j = 0; j < 12; ++j) {
      const int jn = j + 1;
      if (jn < 4)       stageA(jn & 1, cvt8(xf[2*jn], xf[2*jn+1]));
      else if (jn < 12) stageA(jn & 1, h0p[jn-4].v);
      mfma2(&Abuf[j & 1][mu*16 + ra][0], &W0s[nu*16 + ra][j*64]);
      __syncthreads();
    }

    // ---- Q(t-1): hidden under the above; fills ctl and h1c regs ----
    if (t > 0) {
      qphase(t - 1);
    } else {
      #pragma unroll
      for (int q_ = 0; q_ < 8; ++q_) { h1c[q_].u[0] = 0ull; h1c[q_].u[1] = 0ull; }
    }

    // ---- L0 part B: ct chunks 12..13 straight from ctl + cell 0 ----
    mfma2(&ctl[mu*16 + ra][0],  &W0s[nu*16 + ra][768]);
    mfma2(&ctl[mu*16 + ra][64], &W0s[nu*16 + ra][832]);
    {
      f32x4 a = acce + acco;
      #pragma unroll
      for (int r = 0; r < 4; ++r) glds[mu*16 + crow + r][nu*16 + ra] = a[r];
    }
    __syncthreads();
    {
      float gI = glds[srow][ehc]      + bi0;
      float gF = glds[srow][8 + ehc]  + bf0;
      float gG = glds[srow][16 + ehc] + bg0;
      float gO = glds[srow][24 + ehc] + bo0;
      float cn = fsig(gF) * c0r + fsig(gI) * ftanh(gG);
      c0r = cn;
      hstage[srow][ehc] = (f16)(fsig(gO) * ftanh(cn));
    }
    __syncthreads();
    if (wv == 0) {
      uint64_t u0 = *(uint64_t*)&hstage[lane][0];
      uint64_t u1 = *(uint64_t*)&hstage[lane][4];
      astore64(h0c_w + (size_t)lane * 512,     u0);
      astore64(h0c_w + (size_t)lane * 512 + 4, u1);
      asm volatile("s_waitcnt vmcnt(0)" ::: "memory");
      if (lane == 0) flag_add_relaxed(&cntA[(m << 9) + t]);
    }

    // ---- L1: chunks 0..7 (h1_prev from Q regs), 8..15 (h0_cur) ----
    acce = f32x4{0,0,0,0}; acco = f32x4{0,0,0,0};
    stageA(0, h1c[0].v);
    __syncthreads();
    #pragma unroll
    for (int j = 0; j < 16; ++j) {
      if (j == 6) {
        spin(&cntA[(m << 9) + t], 64u);
        #pragma unroll
        for (int q_ = 0; q_ < 8; ++q_) {
          h0c[q_].u[0] = aload64(h0c_b + q_*64);
          h0c[q_].u[1] = aload64(h0c_b + q_*64 + 4);
        }
      }
      const int jn = j + 1;
      if (jn < 8)       stageA(jn & 1, h1c[jn].v);
      else if (jn < 16) stageA(jn & 1, h0c[jn-8].v);
      mfma2(&Abuf[j & 1][mu*16 + ra][0], &W1s[nu*16 + ra][j*64]);
      __syncthreads();
    }
    {
      f32x4 a = acce + acco;
      #pragma unroll
      for (int r = 0; r < 4; ++r) glds[mu*16 + crow + r][nu*16 + ra] = a[r];
    }
    __syncthreads();
    {
      float gI = glds[srow][ehc]      + bi1;
      float gF = glds[srow][8 + ehc]  + bf1;
      float gG = glds[srow][16 + ehc] + bg1;
      float gO = glds[srow][24 + ehc] + bo1;
      float cn = fsig(gF) * c1r + fsig(gI) * ftanh(gG);
      c1r = cn;
      hstage[srow][ehc] = (f16)(fsig(gO) * ftanh(cn));
    }
    __syncthreads();
    if (wv == 0) {
      uint64_t u0 = *(uint64_t*)&hstage[lane][0];
      uint64_t u1 = *(uint64_t*)&hstage[lane][4];
      astore64(h1c_w + (size_t)lane * 512,     u0);
      astore64(h1c_w + (size_t)lane * 512 + 4, u1);
      asm volatile("s_waitcnt vmcnt(0)" ::: "memory");
      if (lane == 0) flag_add_relaxed(&cntB[(m << 9) + t]);
    }
  }

  // ---- tail: final Q for t = TT-1 ----
  qphase(TT - 1);
}

// ---------------- host ----------------
extern "C" void kernel_launch(void* const* d_in, const int* in_sizes, int n_in,
                              void* d_out, int out_size, void* d_ws, size_t ws_size,
                              hipStream_t stream) {
  const float* states = (const float*)d_in[0];
  const float* Wih0 = (const float*)d_in[1];
  const float* Whh0 = (const float*)d_in[2];
  const float* bih0 = (const float*)d_in[3];
  const float* bhh0 = (const float*)d_in[4];
  const float* Wih1 = (const float*)d_in[5];
  const float* Whh1 = (const float*)d_in[6];
  const float* bih1 = (const float*)d_in[7];
  const float* bhh1 = (const float*)d_in[8];
  const float* Wlin = (const float*)d_in[9];
  const float* blin = (const float*)d_in[10];
  float* out = (float*)d_out;
  (void)in_sizes; (void)n_in; (void)out_size;

  char* ws = (char*)d_ws;
  uint32_t* cntA = (uint32_t*)ws;                       // [4][512] = 8192 B
  uint32_t* cntB = (uint32_t*)(ws + 8192);              // 8192 B
  uint32_t* cnt0 = (uint32_t*)(ws + 16384);             // 4 B (pad to 256)
  const size_t cnt_bytes = 16640;
  f16* h0buf = (f16*)(ws + cnt_bytes);                  // 524,288 B
  f16* h1buf = (f16*)(ws + cnt_bytes + 524288);         // 524,288 B
  f16* Wlc   = (f16*)(ws + cnt_bytes + 2 * 524288);     // 131,072 B
  float* noise = (float*)(ws + cnt_bytes + 2 * 524288 + 131072);  // 67,108,864 B
  const size_t need = cnt_bytes + 2 * 524288 + 131072 + 67108864;

  hipMemsetAsync(ws, 0, cnt_bytes, stream);
  if (ws_size >= need) {
    persistent_kernel<true><<<256, 512, 0, stream>>>(
        states, Wih0, Whh0, bih0, bhh0, Wih1, Whh1, bih1, bhh1, Wlin, blin,
        out, cnt0, cntA, cntB, h0buf, h1buf, Wlc, noise);
  } else {
    persistent_kernel<false><<<256, 512, 0, stream>>>(
        states, Wih0, Whh0, bih0, bhh0, Wih1, Whh1, bih1, bhh1, Wlin, blin,
        out, cnt0, cntA, cntB, h0buf, h1buf, Wlc, nullptr);
  }
}